// Round 6
// baseline (462.198 us; speedup 1.0000x reference)
//
#include <hip/hip_runtime.h>
#include <hip/hip_fp16.h>
#include <hip/hip_cooperative_groups.h>

namespace cg = cooperative_groups;

#define N_NODES 100000
#define N_EDGES 1600000
#define MSG 16
#define HID 16
#define NC 32
#define PREP_N 800000       // N*HID/2 packed half2 words == N*MSG/2 m2 words
#define A2_WORDS 1024       // NT*MSG*HID/2 packed half2 words (4 KB)

typedef _Float16 v2h __attribute__((ext_vector_type(2)));

union H2U {
    v2h h;
    unsigned int u;
};

__device__ __forceinline__ float dot2acc(unsigned int a, unsigned int b, float acc) {
    H2U x, y;
    x.u = a; y.u = b;
#if __has_builtin(__builtin_amdgcn_fdot2)
    return __builtin_amdgcn_fdot2(x.h, y.h, acc, false);
#else
    return acc + (float)x.h[0] * (float)y.h[0] + (float)x.h[1] * (float)y.h[1];
#endif
}

__device__ __forceinline__ float fast_sigmoid(float x) {
    return 1.f / (1.f + __expf(-x));
}
__device__ __forceinline__ float fast_tanh(float x) {
    return 2.f / (1.f + __expf(-2.f * x)) - 1.f;
}

// ---------------------------------------------------------------------------
// Phase: prep (grid-stride). feat f32 -> packed fp16 mirror; zero m2;
// pack edge_table to fp16.
// ---------------------------------------------------------------------------
__device__ __forceinline__ void phase_prep(
    int gtid, int gsz,
    const float* __restrict__ feat,
    const float* __restrict__ edge_table,
    unsigned int* __restrict__ feat16,
    unsigned int* __restrict__ m2,
    unsigned int* __restrict__ A2) {
    for (int i = gtid; i < PREP_N; i += gsz) {
        float2 f = reinterpret_cast<const float2*>(feat)[i];
        H2U p;
        p.h[0] = (_Float16)f.x;
        p.h[1] = (_Float16)f.y;
        feat16[i] = p.u;
        m2[i] = 0u;
    }
    for (int i = gtid; i < A2_WORDS; i += gsz) {
        float2 f = reinterpret_cast<const float2*>(edge_table)[i];
        H2U p;
        p.h[0] = (_Float16)f.x;
        p.h[1] = (_Float16)f.y;
        A2[i] = p.u;
    }
}

// ---------------------------------------------------------------------------
// Phase: edge scatter (grid-stride). 8 lanes per edge, lane c computes the
// message pair (2c,2c+1) via v_dot2_f32_f16 from the 3.2 MB L2-resident
// fp16 mirror and the 4 KB A2 table. One fire-and-forget packed-f16 atomic
// per lane into the 3.2 MB m2 (R=1: small atomic footprint is essential).
// Proven 153 G atomics/s at >=16 waves/CU.
// ---------------------------------------------------------------------------
__device__ __forceinline__ void phase_edge(
    long long gtid, long long gsz,
    const int* __restrict__ src,
    const int* __restrict__ dst,
    const int* __restrict__ etype,
    const unsigned int* __restrict__ feat16,
    const unsigned int* __restrict__ A2,
    unsigned int* __restrict__ m2) {
    const long long total = (long long)N_EDGES * 8;
    for (long long t = gtid; t < total; t += gsz) {
        int e = (int)(t >> 3);
        int c = (int)(t & 7);

        int s = src[e];
        int ty = etype[e];
        const uint4* hp = reinterpret_cast<const uint4*>(feat16 + (size_t)s * 8);
        uint4 h0 = hp[0], h1 = hp[1];
        const uint4* ap = reinterpret_cast<const uint4*>(A2 + ty * 128 + c * 16);
        uint4 a0 = ap[0], a1 = ap[1], a2 = ap[2], a3 = ap[3];

        float r0 = 0.f, r1 = 0.f;
        r0 = dot2acc(h0.x, a0.x, r0); r0 = dot2acc(h0.y, a0.y, r0);
        r0 = dot2acc(h0.z, a0.z, r0); r0 = dot2acc(h0.w, a0.w, r0);
        r0 = dot2acc(h1.x, a1.x, r0); r0 = dot2acc(h1.y, a1.y, r0);
        r0 = dot2acc(h1.z, a1.z, r0); r0 = dot2acc(h1.w, a1.w, r0);
        r1 = dot2acc(h0.x, a2.x, r1); r1 = dot2acc(h0.y, a2.y, r1);
        r1 = dot2acc(h0.z, a2.z, r1); r1 = dot2acc(h0.w, a2.w, r1);
        r1 = dot2acc(h1.x, a3.x, r1); r1 = dot2acc(h1.y, a3.y, r1);
        r1 = dot2acc(h1.z, a3.z, r1); r1 = dot2acc(h1.w, a3.w, r1);

        int d = dst[e];
        H2U p;
        p.h[0] = (_Float16)r0;
        p.h[1] = (_Float16)r1;
#if __has_builtin(__builtin_amdgcn_global_atomic_fadd_v2f16)
        __builtin_amdgcn_global_atomic_fadd_v2f16(
            reinterpret_cast<v2h*>(m2 + (size_t)d * 8 + c), p.h);
#endif
    }
}

// ---------------------------------------------------------------------------
// Phase: node (grid-stride), LOW-PRESSURE variant. Per gate j, all six dot
// products run in one k-loop with scalar (wave-uniform) weight loads and the
// GRU nonlinearity is applied immediately -- no srz[32]/i_n[16]/h_n[16]
// arrays. Live set: mv[16] + h[16] + hn[16] + ~8 temps (~80 VGPR), so the
// fused kernel fits __launch_bounds__(256,4)'s 128-VGPR cap without spill.
// ---------------------------------------------------------------------------
__device__ __forceinline__ void phase_node(
    int gtid, int gsz,
    const float* __restrict__ feat,
    const unsigned int* __restrict__ m2,
    const float* __restrict__ W_ih,
    const float* __restrict__ W_hh,
    const float* __restrict__ b_ih,
    const float* __restrict__ b_hh,
    const float* __restrict__ W_out,
    const float* __restrict__ b_out,
    float* __restrict__ out) {
    for (int n = gtid; n < N_NODES; n += gsz) {
        float mv[MSG], h[HID], hn[HID];
        {
            const uint4* mu = reinterpret_cast<const uint4*>(m2 + (size_t)n * 8);
            uint4 a = mu[0], b = mu[1];
            unsigned int w[8] = {a.x, a.y, a.z, a.w, b.x, b.y, b.z, b.w};
            #pragma unroll
            for (int i = 0; i < 8; ++i) {
                H2U hh;
                hh.u = w[i];
                mv[2 * i]     = (float)hh.h[0];
                mv[2 * i + 1] = (float)hh.h[1];
            }
            const float4* f4 = reinterpret_cast<const float4*>(feat + (size_t)n * HID);
            #pragma unroll
            for (int q = 0; q < 4; ++q) {
                float4 v = f4[q];
                h[q * 4 + 0] = v.x; h[q * 4 + 1] = v.y;
                h[q * 4 + 2] = v.z; h[q * 4 + 3] = v.w;
            }
        }

        #pragma unroll 1
        for (int j = 0; j < HID; ++j) {
            const float* wir = W_ih + j * MSG;             // r gate
            const float* whr = W_hh + j * HID;
            const float* wiz = W_ih + (HID + j) * MSG;     // z gate
            const float* whz = W_hh + (HID + j) * HID;
            const float* win = W_ih + (2 * HID + j) * MSG; // n gate
            const float* whn = W_hh + (2 * HID + j) * HID;
            float sr_i = 0.f, sr_h = 0.f, sz_i = 0.f, sz_h = 0.f,
                  sn_i = 0.f, sn_h = 0.f;
            #pragma unroll
            for (int k = 0; k < HID; ++k) {
                float m = mv[k], hv = h[k];
                sr_i += wir[k] * m;  sr_h += whr[k] * hv;
                sz_i += wiz[k] * m;  sz_h += whz[k] * hv;
                sn_i += win[k] * m;  sn_h += whn[k] * hv;
            }
            float r = fast_sigmoid(sr_i + sr_h + b_ih[j] + b_hh[j]);
            float z = fast_sigmoid(sz_i + sz_h + b_ih[HID + j] + b_hh[HID + j]);
            float nn = fast_tanh(sn_i + b_ih[2 * HID + j] +
                                 r * (sn_h + b_hh[2 * HID + j]));
            hn[j] = (1.f - z) * nn + z * h[j];
        }

        float4* op = reinterpret_cast<float4*>(out + (size_t)n * NC);
        #pragma unroll 1
        for (int c4 = 0; c4 < NC / 4; ++c4) {
            float4 o;
            float* oo = &o.x;
            #pragma unroll
            for (int cc = 0; cc < 4; ++cc) {
                int c = c4 * 4 + cc;
                float acc = b_out[c];
                const float* wo = W_out + c * HID;
                #pragma unroll
                for (int k = 0; k < HID; ++k) acc += wo[k] * hn[k];
                oo[cc] = acc;
            }
            op[c4] = o;
        }
    }
}

// ---------------------------------------------------------------------------
// Fused cooperative kernel: prep -> edge -> node, ONE dispatch.
// __launch_bounds__(256, 4): cap 128 VGPR so the node phase cannot throttle
// the atomic-bound edge phase's occupancy (round-5 failure: 256 VGPR -> 2
// waves/SIMD -> edge ~2x slower). 4 blocks/CU -> ~1024-block coop grid.
// ---------------------------------------------------------------------------
__global__ __launch_bounds__(256, 4) void ggnn_fused(
    const float* feat, const int* src, const int* dst, const int* etype,
    const float* edge_table,
    const float* W_ih, const float* W_hh, const float* b_ih, const float* b_hh,
    const float* W_out, const float* b_out,
    float* out, unsigned int* m2, unsigned int* feat16, unsigned int* A2) {
    cg::grid_group grid = cg::this_grid();
    int gtid = blockIdx.x * 256 + threadIdx.x;
    int gsz = gridDim.x * 256;

    phase_prep(gtid, gsz, feat, edge_table, feat16, m2, A2);
    __threadfence();
    grid.sync();

    phase_edge((long long)gtid, (long long)gsz, src, dst, etype, feat16, A2, m2);
    __threadfence();
    grid.sync();

    phase_node(gtid, gsz, feat, m2, W_ih, W_hh, b_ih, b_hh, W_out, b_out, out);
}

// ---------------------------------------------------------------------------
// Standalone kernels: round-0 3-launch path (verified 200 us) as the
// fallback when cooperative launch is unavailable.
// ---------------------------------------------------------------------------
__global__ __launch_bounds__(256) void ggnn_prep_s(
    const float* feat, const float* edge_table,
    unsigned int* feat16, unsigned int* m2, unsigned int* A2) {
    phase_prep(blockIdx.x * 256 + threadIdx.x, gridDim.x * 256,
               feat, edge_table, feat16, m2, A2);
}

__global__ __launch_bounds__(256) void ggnn_edge_s(
    const int* src, const int* dst, const int* etype,
    const unsigned int* feat16, const unsigned int* A2, unsigned int* m2) {
    phase_edge((long long)(blockIdx.x * 256 + threadIdx.x),
               (long long)gridDim.x * 256, src, dst, etype, feat16, A2, m2);
}

__global__ __launch_bounds__(256) void ggnn_node_s(
    const float* feat, const unsigned int* m2,
    const float* W_ih, const float* W_hh, const float* b_ih, const float* b_hh,
    const float* W_out, const float* b_out, float* out) {
    phase_node(blockIdx.x * 256 + threadIdx.x, gridDim.x * 256,
               feat, m2, W_ih, W_hh, b_ih, b_hh, W_out, b_out, out);
}

extern "C" void kernel_launch(void* const* d_in, const int* in_sizes, int n_in,
                              void* d_out, int out_size, void* d_ws, size_t ws_size,
                              hipStream_t stream) {
    const float* feat       = (const float*)d_in[0];
    const int*   src        = (const int*)d_in[1];
    const int*   dst        = (const int*)d_in[2];
    const int*   etype      = (const int*)d_in[3];
    const float* edge_table = (const float*)d_in[4];
    const float* W_ih       = (const float*)d_in[5];
    const float* W_hh       = (const float*)d_in[6];
    const float* b_ih       = (const float*)d_in[7];
    const float* b_hh       = (const float*)d_in[8];
    const float* W_out      = (const float*)d_in[9];
    const float* b_out      = (const float*)d_in[10];
    float* out = (float*)d_out;

    // workspace layout (words): m2 [800K], feat16 [800K], A2 [1K] -> 6.4 MB
    unsigned int* m2     = (unsigned int*)d_ws;
    unsigned int* feat16 = m2 + PREP_N;
    unsigned int* A2     = feat16 + PREP_N;

    // One-time occupancy/CU query for the cooperative grid.
    static int coopBlocks = -2;   // -2 = not yet queried, -1 = unavailable
    if (coopBlocks == -2) {
        int maxB = 0;
        hipError_t oe = hipOccupancyMaxActiveBlocksPerMultiprocessor(
            &maxB, ggnn_fused, 256, 0);
        int cus = 256;
        hipDeviceProp_t prop;
        if (hipGetDeviceProperties(&prop, 0) == hipSuccess &&
            prop.multiProcessorCount > 0)
            cus = prop.multiProcessorCount;
        if (oe == hipSuccess && maxB > 0) {
            if (maxB > 4) maxB = 4;
            coopBlocks = maxB * cus;
        } else {
            coopBlocks = -1;
        }
    }

    if (coopBlocks > 0) {
        void* args[] = {
            (void*)&feat, (void*)&src, (void*)&dst, (void*)&etype,
            (void*)&edge_table,
            (void*)&W_ih, (void*)&W_hh, (void*)&b_ih, (void*)&b_hh,
            (void*)&W_out, (void*)&b_out,
            (void*)&out, (void*)&m2, (void*)&feat16, (void*)&A2
        };
        hipError_t le = hipLaunchCooperativeKernel(
            reinterpret_cast<const void*>(ggnn_fused),
            dim3((unsigned)coopBlocks), dim3(256), args, 0, stream);
        if (le == hipSuccess) return;
        coopBlocks = -1;   // remember failure, fall through
    }

    // Fallback: round-0 3-launch path (verified 200 us).
    int pblocks = (PREP_N + 255) / 256;                  // 3125
    ggnn_prep_s<<<pblocks, 256, 0, stream>>>(feat, edge_table, feat16, m2, A2);

    long long ethreads = (long long)N_EDGES * 8;         // 12.8M
    int eblocks = (int)((ethreads + 255) / 256);         // 50000
    ggnn_edge_s<<<eblocks, 256, 0, stream>>>(src, dst, etype, feat16, A2, m2);

    int nblocks = (N_NODES + 255) / 256;                 // 391
    ggnn_node_s<<<nblocks, 256, 0, stream>>>(feat, m2, W_ih, W_hh, b_ih, b_hh,
                                             W_out, b_out, out);
}